// Round 7
// baseline (400.780 us; speedup 1.0000x reference)
//
#include <hip/hip_runtime.h>

// SelectionGNN clique+line. I/O: float32. Internals: bf16 end-to-end with f32
// accumulation (MFMA + reduce). B=8, N=4096, E=1, K=3, F=[16,32,16],
// MLP 65536->64->1.
// R13: diffuse wave-tile doubled: tile 128x128 (ntiles=32), 4 waves, wave =
//     64x64 (4x4 frags) -> 32 MFMA per barrier interval at 2:1 MFMA:ds
//     (was 32x64/wave: 16 MFMA at 1.33:1 -> est. 143-286 TF, ~1/3 of the
//     m97-structure reference, matching its per-interval-work deficit).
//     Split-K: KS=16 (M=128, ITERS=4) / KS=8 (M=256, ITERS=8); 512 blocks,
//     64 KB LDS 2-buffer -> still 2 blocks/CU. Per iter:
//     {vmcnt(0); s_barrier; stage(i+1); compute(i)}.
//     Enabled by workspace overlay: Scb is dead after layer 2, so Sl reuses
//     the same 32 MB region (Sb) -> 16 MB of partial planes now fit.

#define NN 4096
#define BB 8

typedef unsigned short u16;
typedef unsigned int   u32;

typedef __attribute__((ext_vector_type(8))) short bf16x8;  // 8 bf16 = 4 VGPRs
typedef __attribute__((ext_vector_type(4))) float f32x4;

__device__ __forceinline__ u16 f2bf(float f) {
    union { float f; u32 i; } c; c.f = f;
    u32 i = c.i;
    u32 r = (i + 0x7FFFu + ((i >> 16) & 1u)) >> 16;  // RTNE
    return (u16)r;
}
__device__ __forceinline__ float bf2f(u16 u) {
    union { u32 i; float f; } c; c.i = ((u32)u) << 16; return c.f;
}
__device__ __forceinline__ u32 pack2bf(float lo, float hi) {
    return (u32)f2bf(lo) | ((u32)f2bf(hi) << 16);
}

__device__ __forceinline__ void gload_lds16(const u16* g, u16* l) {
    __builtin_amdgcn_global_load_lds(
        (__attribute__((address_space(1))) void*)g,
        (__attribute__((address_space(3))) void*)l, 16, 0, 0);
}

// ---------------------------------------------------------------------------
// x: 524288 f32 -> bf16. 256 blocks x 256 threads x 8 floats, one shot.
// ---------------------------------------------------------------------------
__global__ __launch_bounds__(256) void cvt_x(const float* __restrict__ in,
                                             u16* __restrict__ out)
{
    const int i = (blockIdx.x * 256 + threadIdx.x) * 8;
    float4 a = *(const float4*)(in + i);
    float4 b = *(const float4*)(in + i + 4);
    uint4 o;
    o.x = pack2bf(a.x, a.y); o.y = pack2bf(a.z, a.w);
    o.z = pack2bf(b.x, b.y); o.w = pack2bf(b.z, b.w);
    *(uint4*)(out + i) = o;
}

// ---------------------------------------------------------------------------
// Split-K diffusion, 128(M) x 128(N) tile, BK=64, bf16 A/B via async LDS:
//   Part[kz][r,n] = sum_{k in slice} Z[r,k] * S[n,k]   (bf16 partial planes)
// LDS: one 64 KB buffer array L: A tiles [0,16K) u16, B tiles [16K,32K) u16,
// 2 buffers each, XOR-swizzled 16B granules slot(r,g) = g ^ (r&7).
// 4 waves in 2x2; wave owns 64x64 via 4x4 mfma_f32_16x16x32_bf16 frags
// (32 MFMA per barrier interval, 16 ds_read_b128 -> 2:1).
// Per iter: vmcnt(0) [my stage(i) landed] ; s_barrier [everyone's landed] ;
// stage(i+1) into buf^1 [safe: all waves passed barrier => finished
// compute(i-1) reads of buf^1] ; compute(i) [hides stage(i+1) latency].
// grid: (32, M/128, KS). blockIdx.x XCD-swizzled (4 consecutive ntiles/XCD).
// Epilogue: per-wave LDS transpose (64 x 72 u16 rows) -> 8x b128 stores.
// ---------------------------------------------------------------------------
template <int ITERS>
__global__ __launch_bounds__(256) void diffuse(const u16* __restrict__ Z,
                                               const u16* __restrict__ S,
                                               u16* __restrict__ Part)
{
    __shared__ u16 L[4 * 128 * 64];   // 64 KB: A@[0,16K), B@[16K,32K) u16 x2buf

    const int bx    = blockIdx.x;                   // 0..31
    const int ntile = ((bx & 7) << 2) | (bx >> 3);  // XCD swizzle
    const int nBase = ntile * 128;
    const int mBase = blockIdx.y * 128;
    const int tid   = threadIdx.x;
    const int lane  = tid & 63;
    const int wv    = tid >> 6;
    const int quad  = lane >> 4;
    const int l16   = lane & 15;
    const int wr    = (wv >> 1) * 64;   // wave row offset in tile
    const int wc    = (wv & 1) * 64;    // wave col offset in tile

    const int kStart = (int)blockIdx.z * (ITERS * 64);

    // async staging: wave-issue = 64 lanes x 16 B = 8 rows x 8 granules
    const int rl   = lane >> 3;
    const int gsl  = lane & 7;
    const int gsrc = gsl ^ rl;

    f32x4 acc[4][4];
#pragma unroll
    for (int i = 0; i < 4; ++i)
#pragma unroll
        for (int j = 0; j < 4; ++j) acc[i][j] = (f32x4){0.f, 0.f, 0.f, 0.f};

    auto stage = [&](int buf, int k0) {
#pragma unroll
        for (int j = 0; j < 4; ++j) {
            const int rb = wv * 32 + j * 8;    // wave's 32 rows of each tile
            gload_lds16(Z + (size_t)(mBase + rb + rl) * NN + k0 + gsrc * 8,
                        &L[buf * 8192 + rb * 64]);
            gload_lds16(S + (size_t)(nBase + rb + rl) * NN + k0 + gsrc * 8,
                        &L[16384 + buf * 8192 + rb * 64]);
        }
    };

    auto compute = [&](int buf) {
#pragma unroll
        for (int s = 0; s < 2; ++s) {
            const int g = s * 4 + quad;        // k-granule 0..7
            bf16x8 af[4], bf[4];
#pragma unroll
            for (int mi = 0; mi < 4; ++mi) {
                const int r = wr + mi * 16 + l16;
                af[mi] = *(const bf16x8*)&L[buf * 8192 + r * 64 + ((g ^ (r & 7)) << 3)];
            }
#pragma unroll
            for (int ni = 0; ni < 4; ++ni) {
                const int r = wc + ni * 16 + l16;
                bf[ni] = *(const bf16x8*)&L[16384 + buf * 8192 + r * 64 + ((g ^ (r & 7)) << 3)];
            }
#pragma unroll
            for (int mi = 0; mi < 4; ++mi)
#pragma unroll
                for (int ni = 0; ni < 4; ++ni)
                    acc[mi][ni] = __builtin_amdgcn_mfma_f32_16x16x32_bf16(
                        af[mi], bf[ni], acc[mi][ni], 0, 0, 0);
        }
    };

    stage(0, kStart);
#pragma unroll
    for (int i = 0; i < ITERS; ++i) {
        asm volatile("s_waitcnt vmcnt(0)" ::: "memory");  // my stage(i) landed
        __builtin_amdgcn_s_barrier();                     // everyone's landed
        if (i + 1 < ITERS) stage((i + 1) & 1, kStart + (i + 1) * 64);
        compute(i & 1);
    }

    // All LDS reads done before reusing L as scratch.
    asm volatile("s_waitcnt lgkmcnt(0)" ::: "memory");
    __builtin_amdgcn_s_barrier();

    // Per-wave transpose region: 64 rows x 72 u16 (144B rows, 16B-aligned).
    // D mapping: col = lane&15, row = quad*4 + reg.
    u16* tb = &L[wv * 4608];
#pragma unroll
    for (int mi = 0; mi < 4; ++mi)
#pragma unroll
        for (int ni = 0; ni < 4; ++ni)
#pragma unroll
            for (int i = 0; i < 4; ++i)
                tb[(mi * 16 + quad * 4 + i) * 72 + ni * 16 + l16] =
                    f2bf(acc[mi][ni][i]);

    const size_t plane = (size_t)gridDim.y * 128 * NN;
    u16* pp = Part + (size_t)blockIdx.z * plane;
    const int row0g = mBase + wr;
    const int col0g = nBase + wc;
#pragma unroll
    for (int j = 0; j < 8; ++j) {
        const int r = (lane >> 3) + j * 8;      // 0..63
        const int c = (lane & 7) * 8;           // 0..56
        bf16x8 v = *(const bf16x8*)&tb[r * 72 + c];
        *(bf16x8*)&pp[(size_t)(row0g + r) * NN + col0g + c] = v;
    }
}

// ---------------------------------------------------------------------------
// Same tile geometry, but with FUSED S conversion (first pass over each S):
// B read in f32 (reg-staged), packed to bf16, ds_write into the swizzled
// slots AND written through to Sb. Plain __syncthreads pipeline (2 one-off
// dispatches; simplicity over peak).
// ---------------------------------------------------------------------------
template <int ITERS>
__global__ __launch_bounds__(256) void diffuse_cvtB(const u16* __restrict__ Z,
                                                    const float* __restrict__ Sf,
                                                    u16* __restrict__ Part,
                                                    u16* __restrict__ Sb)
{
    __shared__ u16 L[4 * 128 * 64];   // 64 KB

    const int bx    = blockIdx.x;
    const int ntile = ((bx & 7) << 2) | (bx >> 3);
    const int nBase = ntile * 128;
    const int mBase = blockIdx.y * 128;
    const int tid   = threadIdx.x;
    const int lane  = tid & 63;
    const int wv    = tid >> 6;
    const int quad  = lane >> 4;
    const int l16   = lane & 15;
    const int wr    = (wv >> 1) * 64;
    const int wc    = (wv & 1) * 64;

    const int kStart = (int)blockIdx.z * (ITERS * 64);

    const int rl   = lane >> 3;
    const int gsl  = lane & 7;
    const int gsrc = gsl ^ rl;

    f32x4 acc[4][4];
#pragma unroll
    for (int i = 0; i < 4; ++i)
#pragma unroll
        for (int j = 0; j < 4; ++j) acc[i][j] = (f32x4){0.f, 0.f, 0.f, 0.f};

    auto stageA = [&](int buf, int k0) {
#pragma unroll
        for (int j = 0; j < 4; ++j) {
            const int rb = wv * 32 + j * 8;
            gload_lds16(Z + (size_t)(mBase + rb + rl) * NN + k0 + gsrc * 8,
                        &L[buf * 8192 + rb * 64]);
        }
    };

    float4 fB[4][2];
    auto loadB = [&](int k0) {
#pragma unroll
        for (int j = 0; j < 4; ++j) {
            const int row = nBase + wv * 32 + j * 8 + rl;
            const float* p = Sf + (size_t)row * NN + k0 + gsrc * 8;
            fB[j][0] = *(const float4*)p;
            fB[j][1] = *(const float4*)(p + 4);
        }
    };
    auto writeB = [&](int buf, int k0) {
#pragma unroll
        for (int j = 0; j < 4; ++j) {
            const int rloc = wv * 32 + j * 8 + rl;        // 0..127 within tile
            bf16x8 v;
            v[0] = (short)f2bf(fB[j][0].x); v[1] = (short)f2bf(fB[j][0].y);
            v[2] = (short)f2bf(fB[j][0].z); v[3] = (short)f2bf(fB[j][0].w);
            v[4] = (short)f2bf(fB[j][1].x); v[5] = (short)f2bf(fB[j][1].y);
            v[6] = (short)f2bf(fB[j][1].z); v[7] = (short)f2bf(fB[j][1].w);
            *(bf16x8*)&L[16384 + buf * 8192 + rloc * 64 + gsl * 8] = v;
            *(bf16x8*)&Sb[(size_t)(nBase + rloc) * NN + k0 + gsrc * 8] = v;
        }
    };

    auto compute = [&](int buf) {
#pragma unroll
        for (int s = 0; s < 2; ++s) {
            const int g = s * 4 + quad;
            bf16x8 af[4], bf[4];
#pragma unroll
            for (int mi = 0; mi < 4; ++mi) {
                const int r = wr + mi * 16 + l16;
                af[mi] = *(const bf16x8*)&L[buf * 8192 + r * 64 + ((g ^ (r & 7)) << 3)];
            }
#pragma unroll
            for (int ni = 0; ni < 4; ++ni) {
                const int r = wc + ni * 16 + l16;
                bf[ni] = *(const bf16x8*)&L[16384 + buf * 8192 + r * 64 + ((g ^ (r & 7)) << 3)];
            }
#pragma unroll
            for (int mi = 0; mi < 4; ++mi)
#pragma unroll
                for (int ni = 0; ni < 4; ++ni)
                    acc[mi][ni] = __builtin_amdgcn_mfma_f32_16x16x32_bf16(
                        af[mi], bf[ni], acc[mi][ni], 0, 0, 0);
        }
    };

    loadB(kStart);
    stageA(0, kStart);
    writeB(0, kStart);
    __syncthreads();

#pragma unroll
    for (int i = 0; i < ITERS; ++i) {
        const int k1 = kStart + (i + 1) * 64;
        if (i + 1 < ITERS) { stageA((i + 1) & 1, k1); loadB(k1); }
        compute(i & 1);
        if (i + 1 < ITERS) writeB((i + 1) & 1, k1);
        __syncthreads();
    }

    u16* tb = &L[wv * 4608];
#pragma unroll
    for (int mi = 0; mi < 4; ++mi)
#pragma unroll
        for (int ni = 0; ni < 4; ++ni)
#pragma unroll
            for (int i = 0; i < 4; ++i)
                tb[(mi * 16 + quad * 4 + i) * 72 + ni * 16 + l16] =
                    f2bf(acc[mi][ni][i]);

    const size_t plane = (size_t)gridDim.y * 128 * NN;
    u16* pp = Part + (size_t)blockIdx.z * plane;
    const int row0g = mBase + wr;
    const int col0g = nBase + wc;
#pragma unroll
    for (int j = 0; j < 8; ++j) {
        const int r = (lane >> 3) + j * 8;
        const int c = (lane & 7) * 8;
        bf16x8 v = *(const bf16x8*)&tb[r * 72 + c];
        *(bf16x8*)&pp[(size_t)(row0g + r) * NN + col0g + c] = v;
    }
}

// ---------------------------------------------------------------------------
// Sum KS bf16 partial planes (f32 accumulate) -> bf16 z.  (z1 only.)
// ---------------------------------------------------------------------------
template <int KS>
__global__ __launch_bounds__(256) void reduce_part(const u16* __restrict__ part,
                                                   int planeElems,
                                                   u16* __restrict__ outb)
{
    const int base   = (blockIdx.x * 256 + threadIdx.x) * 8;
    const int stride = gridDim.x * 256 * 8;
    for (int i = base; i < planeElems; i += stride) {
        float s[8];
#pragma unroll
        for (int e = 0; e < 8; ++e) s[e] = 0.f;
#pragma unroll
        for (int p = 0; p < KS; ++p) {
            uint4 v = *(const uint4*)(part + (size_t)p * planeElems + i);
            const u32 w[4] = {v.x, v.y, v.z, v.w};
#pragma unroll
            for (int q = 0; q < 4; ++q) {
                union { u32 i; float f; } lo, hi;
                lo.i = w[q] << 16;
                hi.i = w[q] & 0xFFFF0000u;
                s[q * 2]     += lo.f;
                s[q * 2 + 1] += hi.f;
            }
        }
        uint4 o;
        o.x = (u32)f2bf(s[0]) | ((u32)f2bf(s[1]) << 16);
        o.y = (u32)f2bf(s[2]) | ((u32)f2bf(s[3]) << 16);
        o.z = (u32)f2bf(s[4]) | ((u32)f2bf(s[5]) << 16);
        o.w = (u32)f2bf(s[6]) | ((u32)f2bf(s[7]) << 16);
        *(uint4*)(outb + i) = o;
    }
}

// ---------------------------------------------------------------------------
// Tap combine + ReLU, bf16 in/out (f32 math). Tap 2 read directly from the
// KS bf16 partial planes (fused reduce):
// out[b,g,n] = relu( bias[g] + sum_k sum_f W[g,k,f] * z_k[b,f,n] )
// ---------------------------------------------------------------------------
template <int FIN, int FOUT, int KS>
__global__ __launch_bounds__(256) void combine_relu(
    const u16* __restrict__ z0, const u16* __restrict__ z1,
    const u16* __restrict__ part2, int planeElems,
    const float* __restrict__ W, const float* __restrict__ bias,
    u16* __restrict__ out)
{
    __shared__ float hs[FOUT * 3 * FIN];
    __shared__ float bs[FOUT];
    for (int i = threadIdx.x; i < FOUT * 3 * FIN; i += 256) hs[i] = W[i];
    if (threadIdx.x < FOUT) bs[threadIdx.x] = bias[threadIdx.x];
    __syncthreads();

    const int nb = NN / 256;                 // 16
    const int b  = blockIdx.x / nb;
    const int n  = (blockIdx.x % nb) * 256 + threadIdx.x;

    float zv[3][FIN];
    const u16* zp0 = z0 + (size_t)b * FIN * NN + n;
    const u16* zp1 = z1 + (size_t)b * FIN * NN + n;
    const u16* zp2 = part2 + (size_t)b * FIN * NN + n;
#pragma unroll
    for (int f = 0; f < FIN; ++f) {
        zv[0][f] = bf2f(zp0[(size_t)f * NN]);
        zv[1][f] = bf2f(zp1[(size_t)f * NN]);
        float s = 0.f;
#pragma unroll
        for (int p = 0; p < KS; ++p)
            s += bf2f(zp2[(size_t)p * planeElems + (size_t)f * NN]);
        zv[2][f] = s;
    }

    u16* op = out + (size_t)b * FOUT * NN + n;
    for (int g = 0; g < FOUT; ++g) {
        float acc = bs[g];
#pragma unroll
        for (int k = 0; k < 3; ++k)
#pragma unroll
            for (int f = 0; f < FIN; ++f)
                acc = fmaf(hs[(g * 3 + k) * FIN + f], zv[k][f], acc);
        op[(size_t)g * NN] = f2bf(fmaxf(acc, 0.f));
    }
}

// ---------------------------------------------------------------------------
// MLP layer 1, split-K: h1p[slice][b][j] = sum_{slice} y[b,i]*Wm1[j,i].
// ---------------------------------------------------------------------------
__global__ __launch_bounds__(256) void mlp1(const u16* __restrict__ y,
                                            const float* __restrict__ Wm1,
                                            float* __restrict__ h1p)
{
    const int j    = blockIdx.x;
    const int base = blockIdx.y * 8192;
    const int D    = 16 * NN;  // 65536

    float acc[BB];
#pragma unroll
    for (int b = 0; b < BB; ++b) acc[b] = 0.f;

    const float* wrow = Wm1 + (size_t)j * D + base;
    for (int idx = threadIdx.x * 8; idx < 8192; idx += 256 * 8) {
        float4 w0 = *(const float4*)(wrow + idx);
        float4 w1 = *(const float4*)(wrow + idx + 4);
#pragma unroll
        for (int b = 0; b < BB; ++b) {
            uint4 yv = *(const uint4*)(y + (size_t)b * D + base + idx);
            union { u32 i; float f; } c[8];
            c[0].i = yv.x << 16; c[1].i = yv.x & 0xFFFF0000u;
            c[2].i = yv.y << 16; c[3].i = yv.y & 0xFFFF0000u;
            c[4].i = yv.z << 16; c[5].i = yv.z & 0xFFFF0000u;
            c[6].i = yv.w << 16; c[7].i = yv.w & 0xFFFF0000u;
            acc[b] = fmaf(w0.x, c[0].f, acc[b]);
            acc[b] = fmaf(w0.y, c[1].f, acc[b]);
            acc[b] = fmaf(w0.z, c[2].f, acc[b]);
            acc[b] = fmaf(w0.w, c[3].f, acc[b]);
            acc[b] = fmaf(w1.x, c[4].f, acc[b]);
            acc[b] = fmaf(w1.y, c[5].f, acc[b]);
            acc[b] = fmaf(w1.z, c[6].f, acc[b]);
            acc[b] = fmaf(w1.w, c[7].f, acc[b]);
        }
    }

    __shared__ float red[BB][4];
    const int lane = threadIdx.x & 63;
    const int w    = threadIdx.x >> 6;
#pragma unroll
    for (int b = 0; b < BB; ++b) {
        float v = acc[b];
        for (int off = 32; off > 0; off >>= 1) v += __shfl_down(v, off, 64);
        if (lane == 0) red[b][w] = v;
    }
    __syncthreads();
    if (threadIdx.x < BB) {
        const int b = threadIdx.x;
        h1p[blockIdx.y * (BB * 64) + b * 64 + j] =
            red[b][0] + red[b][1] + red[b][2] + red[b][3];
    }
}

// ---------------------------------------------------------------------------
// MLP layer 2 (+ slice-sum + layer-1 bias/ReLU). 1 block, 64 lanes.
// ---------------------------------------------------------------------------
__global__ void mlp2(const float* __restrict__ h1p,
                     const float* __restrict__ bm1,
                     const float* __restrict__ Wm2,
                     const float* __restrict__ bm2, float* __restrict__ out)
{
    const int lane = threadIdx.x;  // 0..63
    const float w    = Wm2[lane];
    const float b1   = bm1[lane];
    const float bias = bm2[0];
    for (int b = 0; b < BB; ++b) {
        float h = 0.f;
#pragma unroll
        for (int p = 0; p < 8; ++p) h += h1p[p * (BB * 64) + b * 64 + lane];
        float v = fmaxf(h + b1, 0.f) * w;
        for (int off = 32; off > 0; off >>= 1) v += __shfl_down(v, off, 64);
        if (lane == 0) out[b] = v + bias;
    }
}

// ---------------------------------------------------------------------------
extern "C" void kernel_launch(void* const* d_in, const int* in_sizes, int n_in,
                              void* d_out, int out_size, void* d_ws, size_t ws_size,
                              hipStream_t stream)
{
    const float* x   = (const float*)d_in[0];   // [8,16,4096]
    const float* Sc  = (const float*)d_in[1];   // [1,4096,4096]
    const float* Sl  = (const float*)d_in[2];   // [1,4096,4096]
    const float* Wc1 = (const float*)d_in[3];
    const float* bc1 = (const float*)d_in[4];
    const float* Wc2 = (const float*)d_in[5];
    const float* bc2 = (const float*)d_in[6];
    const float* Wl1 = (const float*)d_in[7];
    const float* bl1 = (const float*)d_in[8];
    const float* Wl2 = (const float*)d_in[9];
    const float* bl2 = (const float*)d_in[10];
    const float* Wm1 = (const float*)d_in[11];  // [64,65536]
    const float* bm1 = (const float*)d_in[12];
    const float* Wm2 = (const float*)d_in[13];  // [1,64]
    const float* bm2 = (const float*)d_in[14];
    float* out = (float*)d_out;                 // [8,1] f32

    char* ws = (char*)d_ws;                      // proven >= 81.02 MB
    u16*   part = (u16*)(ws);                    // 16 MB partial planes
    u16*   zb1  = (u16*)(ws + (16u << 20));      // 2 MB
    u16*   yPa  = (u16*)(ws + (18u << 20));      // 2 MB
    u16*   yPb  = (u16*)(ws + (20u << 20));      // 2 MB
    float* h1p  = (float*)(ws + (22u << 20));    // 16 KB (8 slices x 8 x 64)
    u16*   Sb   = (u16*)(ws + (23u << 20));      // 32 MB SHARED Scb/Slb
                                                 // (Scb dead after layer 2)

    const dim3 blk(256);
    const dim3 gridCmb(BB * NN / 256);           // 128
    const dim3 g128(32, 1, 16);                  // M=128: 512 blocks, ITERS=4
    const dim3 g256(32, 2, 8);                   // M=256: 512 blocks, ITERS=8
    const int  pl128 = 128 * NN;                 // plane elems, M=128
    const int  pl256 = 256 * NN;                 // plane elems, M=256

    cvt_x<<<256, blk, 0, stream>>>(x, yPa);

    // Layer 1: clique, Fin=16 (M=128) -> Fout=32.  First pass over Sc reads
    // f32 and writes Sb (bf16) as byproduct.
    diffuse_cvtB<4><<<g128, blk, 0, stream>>>(yPa, Sc, part, Sb);
    reduce_part<16><<<256, blk, 0, stream>>>(part, pl128, zb1);
    diffuse<4><<<g128, blk, 0, stream>>>(zb1, Sb, part);
    combine_relu<16, 32, 16><<<gridCmb, blk, 0, stream>>>(yPa, zb1, part, pl128,
                                                          Wc1, bc1, yPb);
    // Layer 2: clique, Fin=32 (M=256) -> Fout=16
    diffuse<8><<<g256, blk, 0, stream>>>(yPb, Sb, part);
    reduce_part<8><<<512, blk, 0, stream>>>(part, pl256, zb1);
    diffuse<8><<<g256, blk, 0, stream>>>(zb1, Sb, part);
    combine_relu<32, 16, 8><<<gridCmb, blk, 0, stream>>>(yPb, zb1, part, pl256,
                                                         Wc2, bc2, yPa);
    // Layer 3: line, Fin=16 (M=128) -> Fout=32.  First pass over Sl reads
    // f32 and OVERWRITES Sb with bf16 Sl.
    diffuse_cvtB<4><<<g128, blk, 0, stream>>>(yPa, Sl, part, Sb);
    reduce_part<16><<<256, blk, 0, stream>>>(part, pl128, zb1);
    diffuse<4><<<g128, blk, 0, stream>>>(zb1, Sb, part);
    combine_relu<16, 32, 16><<<gridCmb, blk, 0, stream>>>(yPa, zb1, part, pl128,
                                                          Wl1, bl1, yPb);
    // Layer 4: line, Fin=32 (M=256) -> Fout=16
    diffuse<8><<<g256, blk, 0, stream>>>(yPb, Sb, part);
    reduce_part<8><<<512, blk, 0, stream>>>(part, pl256, zb1);
    diffuse<8><<<g256, blk, 0, stream>>>(zb1, Sb, part);
    combine_relu<32, 16, 8><<<gridCmb, blk, 0, stream>>>(yPb, zb1, part, pl256,
                                                         Wl2, bl2, yPa);
    // MLP
    mlp1<<<dim3(64, 8), blk, 0, stream>>>(yPa, Wm1, h1p);
    mlp2<<<1, 64, 0, stream>>>(h1p, bm1, Wm2, bm2, out);
}

// Round 9
// 367.347 us; speedup vs baseline: 1.0910x; 1.0910x over previous
//
#include <hip/hip_runtime.h>

// SelectionGNN clique+line. I/O: float32. Internals: bf16 end-to-end with f32
// accumulation (MFMA + reduce). B=8, N=4096, E=1, K=3, F=[16,32,16],
// MLP 65536->64->1.
// R15: R14's cooperative fusion abandoned (hipLaunchCooperativeKernel is not
//     graph-capturable -> launches silently no-op'd -> zero outputs).
//     This round = R13's verified-correct 128x128 tile geometry combined
//     with R12's proven 3-buffer depth-2 counted-vmcnt schedule, with KS
//     kept at 8/4 (R12 numerics, R12 partial-plane traffic):
//     - wave = 64x64 (4x4 frags): per interval 32 MFMA : 16 ds_read :
//       8 gload per wave (2x the MFMA work per staged byte of R12).
//     - grid (32,1,8) / (32,2,4) = 256 blocks, ITERS=8/16.
//     - LDS 96 KB (3 x 16KB A + 3 x 16KB B) -> 1 block/CU, 4 waves.
//     - vmcnt(16/8/0) counted waits (8 gloads/stage/wave, depth 2).
//     Everything else (cvt_x, reduce, combine, mlp1/2, workspace) = R12.

#define NN 4096
#define BB 8

typedef unsigned short u16;
typedef unsigned int   u32;

typedef __attribute__((ext_vector_type(8))) short bf16x8;  // 8 bf16 = 4 VGPRs
typedef __attribute__((ext_vector_type(4))) float f32x4;

__device__ __forceinline__ u16 f2bf(float f) {
    union { float f; u32 i; } c; c.f = f;
    u32 i = c.i;
    u32 r = (i + 0x7FFFu + ((i >> 16) & 1u)) >> 16;  // RTNE
    return (u16)r;
}
__device__ __forceinline__ float bf2f(u16 u) {
    union { u32 i; float f; } c; c.i = ((u32)u) << 16; return c.f;
}
__device__ __forceinline__ u32 pack2bf(float lo, float hi) {
    return (u32)f2bf(lo) | ((u32)f2bf(hi) << 16);
}

__device__ __forceinline__ void gload_lds16(const u16* g, u16* l) {
    __builtin_amdgcn_global_load_lds(
        (__attribute__((address_space(1))) void*)g,
        (__attribute__((address_space(3))) void*)l, 16, 0, 0);
}

// ---------------------------------------------------------------------------
// x: 524288 f32 -> bf16. 256 blocks x 256 threads x 8 floats, one shot.
// ---------------------------------------------------------------------------
__global__ __launch_bounds__(256) void cvt_x(const float* __restrict__ in,
                                             u16* __restrict__ out)
{
    const int i = (blockIdx.x * 256 + threadIdx.x) * 8;
    float4 a = *(const float4*)(in + i);
    float4 b = *(const float4*)(in + i + 4);
    uint4 o;
    o.x = pack2bf(a.x, a.y); o.y = pack2bf(a.z, a.w);
    o.z = pack2bf(b.x, b.y); o.w = pack2bf(b.z, b.w);
    *(uint4*)(out + i) = o;
}

// ---------------------------------------------------------------------------
// Split-K diffusion, 128(M) x 128(N) tile, BK=64, bf16 A/B via async LDS:
//   Part[kz][r,n] = sum_{k in slice} Z[r,k] * S[n,k]   (bf16 partial planes)
// LDS 96 KB: A = L[0..24576) u16 (3 x 8192), B = L[24576..49152) (3 x 8192).
// XOR-swizzled 16B granules: slot(r,g) = g ^ (r&7).
// 4 waves in 2x2; wave owns 64x64 via 4x4 mfma frags: per interval 32 MFMA,
// 16 ds_read_b128, 8 gload_lds (2:1 MFMA:ds).
// R12-proven schedule, scaled: stage(0); stage(1); per iter i:
//   [stage(i+2)] ; s_waitcnt vmcnt(16|8|0) ; s_barrier ; compute(i) ;
//   [s_barrier]. Counted vmcnt keeps 2 staged tiles in flight (T4).
// grid: (32, M/128, KS). Epilogue: per-wave LDS transpose (64 x 72 u16) ->
// 8x global b128 stores per lane.
// ---------------------------------------------------------------------------
template <int ITERS>
__global__ __launch_bounds__(256) void diffuse(const u16* __restrict__ Z,
                                               const u16* __restrict__ S,
                                               u16* __restrict__ Part)
{
    __shared__ u16 L[6 * 8192];   // 96 KB

    const int bx    = blockIdx.x;                   // 0..31
    const int ntile = ((bx & 7) << 2) | (bx >> 3);  // XCD swizzle
    const int nBase = ntile * 128;
    const int mBase = blockIdx.y * 128;
    const int tid   = threadIdx.x;
    const int lane  = tid & 63;
    const int wv    = tid >> 6;
    const int quad  = lane >> 4;
    const int l16   = lane & 15;
    const int wr    = (wv >> 1) * 64;   // wave row offset in tile
    const int wc    = (wv & 1) * 64;    // wave col offset in tile

    const int kStart = (int)blockIdx.z * (ITERS * 64);

    // async staging: wave-issue = 64 lanes x 16 B = 8 rows x 8 granules
    const int rl   = lane >> 3;
    const int gsl  = lane & 7;
    const int gsrc = gsl ^ rl;

    f32x4 acc[4][4];
#pragma unroll
    for (int i = 0; i < 4; ++i)
#pragma unroll
        for (int j = 0; j < 4; ++j) acc[i][j] = (f32x4){0.f, 0.f, 0.f, 0.f};

    auto stage = [&](int buf, int k0) {
#pragma unroll
        for (int j = 0; j < 4; ++j) {
            const int rb = wv * 32 + j * 8;    // wave's 32 rows of each tile
            gload_lds16(Z + (size_t)(mBase + rb + rl) * NN + k0 + gsrc * 8,
                        &L[buf * 8192 + rb * 64]);
            gload_lds16(S + (size_t)(nBase + rb + rl) * NN + k0 + gsrc * 8,
                        &L[24576 + buf * 8192 + rb * 64]);
        }
    };

    auto compute = [&](int buf) {
#pragma unroll
        for (int s = 0; s < 2; ++s) {
            const int g = s * 4 + quad;        // k-granule 0..7
            bf16x8 af[4], bf[4];
#pragma unroll
            for (int mi = 0; mi < 4; ++mi) {
                const int r = wr + mi * 16 + l16;
                af[mi] = *(const bf16x8*)&L[buf * 8192 + r * 64 + ((g ^ (r & 7)) << 3)];
            }
#pragma unroll
            for (int ni = 0; ni < 4; ++ni) {
                const int r = wc + ni * 16 + l16;
                bf[ni] = *(const bf16x8*)&L[24576 + buf * 8192 + r * 64 + ((g ^ (r & 7)) << 3)];
            }
#pragma unroll
            for (int mi = 0; mi < 4; ++mi)
#pragma unroll
                for (int ni = 0; ni < 4; ++ni)
                    acc[mi][ni] = __builtin_amdgcn_mfma_f32_16x16x32_bf16(
                        af[mi], bf[ni], acc[mi][ni], 0, 0, 0);
        }
    };

    // prologue: two tiles in flight before first wait
    stage(0, kStart);
    stage(1, kStart + 64);

#pragma unroll
    for (int i = 0; i < ITERS; ++i) {
        if (i + 2 < ITERS) stage((i + 2) % 3, kStart + (i + 2) * 64);
        if (i < ITERS - 2)
            asm volatile("s_waitcnt vmcnt(16)" ::: "memory");  // stage(i) landed
        else if (i == ITERS - 2)
            asm volatile("s_waitcnt vmcnt(8)" ::: "memory");
        else
            asm volatile("s_waitcnt vmcnt(0)" ::: "memory");
        __builtin_amdgcn_s_barrier();          // raw barrier: no vmcnt drain
        compute(i % 3);
        if (i + 1 < ITERS) __builtin_amdgcn_s_barrier();  // guard buf reuse
    }

    // All LDS reads done before reusing L as scratch.
    asm volatile("s_waitcnt lgkmcnt(0)" ::: "memory");
    __builtin_amdgcn_s_barrier();

    // Per-wave transpose region: 64 rows x 72 u16 (144B rows, 16B-aligned).
    // D mapping: col = lane&15, row = quad*4 + reg.
    u16* tb = &L[wv * 4608];
#pragma unroll
    for (int mi = 0; mi < 4; ++mi)
#pragma unroll
        for (int ni = 0; ni < 4; ++ni)
#pragma unroll
            for (int i = 0; i < 4; ++i)
                tb[(mi * 16 + quad * 4 + i) * 72 + ni * 16 + l16] =
                    f2bf(acc[mi][ni][i]);

    const size_t plane = (size_t)gridDim.y * 128 * NN;
    u16* pp = Part + (size_t)blockIdx.z * plane;
    const int row0g = mBase + wr;
    const int col0g = nBase + wc;
#pragma unroll
    for (int j = 0; j < 8; ++j) {
        const int r = (lane >> 3) + j * 8;      // 0..63
        const int c = (lane & 7) * 8;           // 0..56
        bf16x8 v = *(const bf16x8*)&tb[r * 72 + c];
        *(bf16x8*)&pp[(size_t)(row0g + r) * NN + col0g + c] = v;
    }
}

// ---------------------------------------------------------------------------
// Same tile geometry with FUSED S conversion (first pass over each S):
// B read in f32 (reg-staged), packed to bf16, ds_write into the swizzled
// slots AND written through to Sb. 2-buffer __syncthreads pipeline (2 one-off
// dispatches; R13-verified logic).
// ---------------------------------------------------------------------------
template <int ITERS>
__global__ __launch_bounds__(256) void diffuse_cvtB(const u16* __restrict__ Z,
                                                    const float* __restrict__ Sf,
                                                    u16* __restrict__ Part,
                                                    u16* __restrict__ Sb)
{
    __shared__ u16 L[4 * 8192];   // 64 KB: A 2x8192 @0, B 2x8192 @16384

    const int bx    = blockIdx.x;
    const int ntile = ((bx & 7) << 2) | (bx >> 3);
    const int nBase = ntile * 128;
    const int mBase = blockIdx.y * 128;
    const int tid   = threadIdx.x;
    const int lane  = tid & 63;
    const int wv    = tid >> 6;
    const int quad  = lane >> 4;
    const int l16   = lane & 15;
    const int wr    = (wv >> 1) * 64;
    const int wc    = (wv & 1) * 64;

    const int kStart = (int)blockIdx.z * (ITERS * 64);

    const int rl   = lane >> 3;
    const int gsl  = lane & 7;
    const int gsrc = gsl ^ rl;

    f32x4 acc[4][4];
#pragma unroll
    for (int i = 0; i < 4; ++i)
#pragma unroll
        for (int j = 0; j < 4; ++j) acc[i][j] = (f32x4){0.f, 0.f, 0.f, 0.f};

    auto stageA = [&](int buf, int k0) {
#pragma unroll
        for (int j = 0; j < 4; ++j) {
            const int rb = wv * 32 + j * 8;
            gload_lds16(Z + (size_t)(mBase + rb + rl) * NN + k0 + gsrc * 8,
                        &L[buf * 8192 + rb * 64]);
        }
    };

    float4 fB[4][2];
    auto loadB = [&](int k0) {
#pragma unroll
        for (int j = 0; j < 4; ++j) {
            const int row = nBase + wv * 32 + j * 8 + rl;
            const float* p = Sf + (size_t)row * NN + k0 + gsrc * 8;
            fB[j][0] = *(const float4*)p;
            fB[j][1] = *(const float4*)(p + 4);
        }
    };
    auto writeB = [&](int buf, int k0) {
#pragma unroll
        for (int j = 0; j < 4; ++j) {
            const int rloc = wv * 32 + j * 8 + rl;        // 0..127 within tile
            bf16x8 v;
            v[0] = (short)f2bf(fB[j][0].x); v[1] = (short)f2bf(fB[j][0].y);
            v[2] = (short)f2bf(fB[j][0].z); v[3] = (short)f2bf(fB[j][0].w);
            v[4] = (short)f2bf(fB[j][1].x); v[5] = (short)f2bf(fB[j][1].y);
            v[6] = (short)f2bf(fB[j][1].z); v[7] = (short)f2bf(fB[j][1].w);
            *(bf16x8*)&L[16384 + buf * 8192 + rloc * 64 + gsl * 8] = v;
            *(bf16x8*)&Sb[(size_t)(nBase + rloc) * NN + k0 + gsrc * 8] = v;
        }
    };

    auto compute = [&](int buf) {
#pragma unroll
        for (int s = 0; s < 2; ++s) {
            const int g = s * 4 + quad;
            bf16x8 af[4], bf[4];
#pragma unroll
            for (int mi = 0; mi < 4; ++mi) {
                const int r = wr + mi * 16 + l16;
                af[mi] = *(const bf16x8*)&L[buf * 8192 + r * 64 + ((g ^ (r & 7)) << 3)];
            }
#pragma unroll
            for (int ni = 0; ni < 4; ++ni) {
                const int r = wc + ni * 16 + l16;
                bf[ni] = *(const bf16x8*)&L[16384 + buf * 8192 + r * 64 + ((g ^ (r & 7)) << 3)];
            }
#pragma unroll
            for (int mi = 0; mi < 4; ++mi)
#pragma unroll
                for (int ni = 0; ni < 4; ++ni)
                    acc[mi][ni] = __builtin_amdgcn_mfma_f32_16x16x32_bf16(
                        af[mi], bf[ni], acc[mi][ni], 0, 0, 0);
        }
    };

    loadB(kStart);
    stageA(0, kStart);
    writeB(0, kStart);
    __syncthreads();

#pragma unroll
    for (int i = 0; i < ITERS; ++i) {
        const int k1 = kStart + (i + 1) * 64;
        if (i + 1 < ITERS) { stageA((i + 1) & 1, k1); loadB(k1); }
        compute(i & 1);
        if (i + 1 < ITERS) writeB((i + 1) & 1, k1);
        __syncthreads();
    }

    u16* tb = &L[wv * 4608];
#pragma unroll
    for (int mi = 0; mi < 4; ++mi)
#pragma unroll
        for (int ni = 0; ni < 4; ++ni)
#pragma unroll
            for (int i = 0; i < 4; ++i)
                tb[(mi * 16 + quad * 4 + i) * 72 + ni * 16 + l16] =
                    f2bf(acc[mi][ni][i]);

    const size_t plane = (size_t)gridDim.y * 128 * NN;
    u16* pp = Part + (size_t)blockIdx.z * plane;
    const int row0g = mBase + wr;
    const int col0g = nBase + wc;
#pragma unroll
    for (int j = 0; j < 8; ++j) {
        const int r = (lane >> 3) + j * 8;
        const int c = (lane & 7) * 8;
        bf16x8 v = *(const bf16x8*)&tb[r * 72 + c];
        *(bf16x8*)&pp[(size_t)(row0g + r) * NN + col0g + c] = v;
    }
}

// ---------------------------------------------------------------------------
// Sum KS bf16 partial planes (f32 accumulate) -> bf16 z.  (z1 only.)
// ---------------------------------------------------------------------------
template <int KS>
__global__ __launch_bounds__(256) void reduce_part(const u16* __restrict__ part,
                                                   int planeElems,
                                                   u16* __restrict__ outb)
{
    const int base   = (blockIdx.x * 256 + threadIdx.x) * 8;
    const int stride = gridDim.x * 256 * 8;
    for (int i = base; i < planeElems; i += stride) {
        float s[8];
#pragma unroll
        for (int e = 0; e < 8; ++e) s[e] = 0.f;
#pragma unroll
        for (int p = 0; p < KS; ++p) {
            uint4 v = *(const uint4*)(part + (size_t)p * planeElems + i);
            const u32 w[4] = {v.x, v.y, v.z, v.w};
#pragma unroll
            for (int q = 0; q < 4; ++q) {
                union { u32 i; float f; } lo, hi;
                lo.i = w[q] << 16;
                hi.i = w[q] & 0xFFFF0000u;
                s[q * 2]     += lo.f;
                s[q * 2 + 1] += hi.f;
            }
        }
        uint4 o;
        o.x = (u32)f2bf(s[0]) | ((u32)f2bf(s[1]) << 16);
        o.y = (u32)f2bf(s[2]) | ((u32)f2bf(s[3]) << 16);
        o.z = (u32)f2bf(s[4]) | ((u32)f2bf(s[5]) << 16);
        o.w = (u32)f2bf(s[6]) | ((u32)f2bf(s[7]) << 16);
        *(uint4*)(outb + i) = o;
    }
}

// ---------------------------------------------------------------------------
// Tap combine + ReLU, bf16 in/out (f32 math). Tap 2 read directly from the
// KS bf16 partial planes (fused reduce):
// out[b,g,n] = relu( bias[g] + sum_k sum_f W[g,k,f] * z_k[b,f,n] )
// ---------------------------------------------------------------------------
template <int FIN, int FOUT, int KS>
__global__ __launch_bounds__(256) void combine_relu(
    const u16* __restrict__ z0, const u16* __restrict__ z1,
    const u16* __restrict__ part2, int planeElems,
    const float* __restrict__ W, const float* __restrict__ bias,
    u16* __restrict__ out)
{
    __shared__ float hs[FOUT * 3 * FIN];
    __shared__ float bs[FOUT];
    for (int i = threadIdx.x; i < FOUT * 3 * FIN; i += 256) hs[i] = W[i];
    if (threadIdx.x < FOUT) bs[threadIdx.x] = bias[threadIdx.x];
    __syncthreads();

    const int nb = NN / 256;                 // 16
    const int b  = blockIdx.x / nb;
    const int n  = (blockIdx.x % nb) * 256 + threadIdx.x;

    float zv[3][FIN];
    const u16* zp0 = z0 + (size_t)b * FIN * NN + n;
    const u16* zp1 = z1 + (size_t)b * FIN * NN + n;
    const u16* zp2 = part2 + (size_t)b * FIN * NN + n;
#pragma unroll
    for (int f = 0; f < FIN; ++f) {
        zv[0][f] = bf2f(zp0[(size_t)f * NN]);
        zv[1][f] = bf2f(zp1[(size_t)f * NN]);
        float s = 0.f;
#pragma unroll
        for (int p = 0; p < KS; ++p)
            s += bf2f(zp2[(size_t)p * planeElems + (size_t)f * NN]);
        zv[2][f] = s;
    }

    u16* op = out + (size_t)b * FOUT * NN + n;
    for (int g = 0; g < FOUT; ++g) {
        float acc = bs[g];
#pragma unroll
        for (int k = 0; k < 3; ++k)
#pragma unroll
            for (int f = 0; f < FIN; ++f)
                acc = fmaf(hs[(g * 3 + k) * FIN + f], zv[k][f], acc);
        op[(size_t)g * NN] = f2bf(fmaxf(acc, 0.f));
    }
}

// ---------------------------------------------------------------------------
// MLP layer 1, split-K: h1p[slice][b][j] = sum_{slice} y[b,i]*Wm1[j,i].
// ---------------------------------------------------------------------------
__global__ __launch_bounds__(256) void mlp1(const u16* __restrict__ y,
                                            const float* __restrict__ Wm1,
                                            float* __restrict__ h1p)
{
    const int j    = blockIdx.x;
    const int base = blockIdx.y * 8192;
    const int D    = 16 * NN;  // 65536

    float acc[BB];
#pragma unroll
    for (int b = 0; b < BB; ++b) acc[b] = 0.f;

    const float* wrow = Wm1 + (size_t)j * D + base;
    for (int idx = threadIdx.x * 8; idx < 8192; idx += 256 * 8) {
        float4 w0 = *(const float4*)(wrow + idx);
        float4 w1 = *(const float4*)(wrow + idx + 4);
#pragma unroll
        for (int b = 0; b < BB; ++b) {
            uint4 yv = *(const uint4*)(y + (size_t)b * D + base + idx);
            union { u32 i; float f; } c[8];
            c[0].i = yv.x << 16; c[1].i = yv.x & 0xFFFF0000u;
            c[2].i = yv.y << 16; c[3].i = yv.y & 0xFFFF0000u;
            c[4].i = yv.z << 16; c[5].i = yv.z & 0xFFFF0000u;
            c[6].i = yv.w << 16; c[7].i = yv.w & 0xFFFF0000u;
            acc[b] = fmaf(w0.x, c[0].f, acc[b]);
            acc[b] = fmaf(w0.y, c[1].f, acc[b]);
            acc[b] = fmaf(w0.z, c[2].f, acc[b]);
            acc[b] = fmaf(w0.w, c[3].f, acc[b]);
            acc[b] = fmaf(w1.x, c[4].f, acc[b]);
            acc[b] = fmaf(w1.y, c[5].f, acc[b]);
            acc[b] = fmaf(w1.z, c[6].f, acc[b]);
            acc[b] = fmaf(w1.w, c[7].f, acc[b]);
        }
    }

    __shared__ float red[BB][4];
    const int lane = threadIdx.x & 63;
    const int w    = threadIdx.x >> 6;
#pragma unroll
    for (int b = 0; b < BB; ++b) {
        float v = acc[b];
        for (int off = 32; off > 0; off >>= 1) v += __shfl_down(v, off, 64);
        if (lane == 0) red[b][w] = v;
    }
    __syncthreads();
    if (threadIdx.x < BB) {
        const int b = threadIdx.x;
        h1p[blockIdx.y * (BB * 64) + b * 64 + j] =
            red[b][0] + red[b][1] + red[b][2] + red[b][3];
    }
}

// ---------------------------------------------------------------------------
// MLP layer 2 (+ slice-sum + layer-1 bias/ReLU). 1 block, 64 lanes.
// ---------------------------------------------------------------------------
__global__ void mlp2(const float* __restrict__ h1p,
                     const float* __restrict__ bm1,
                     const float* __restrict__ Wm2,
                     const float* __restrict__ bm2, float* __restrict__ out)
{
    const int lane = threadIdx.x;  // 0..63
    const float w    = Wm2[lane];
    const float b1   = bm1[lane];
    const float bias = bm2[0];
    for (int b = 0; b < BB; ++b) {
        float h = 0.f;
#pragma unroll
        for (int p = 0; p < 8; ++p) h += h1p[p * (BB * 64) + b * 64 + lane];
        float v = fmaxf(h + b1, 0.f) * w;
        for (int off = 32; off > 0; off >>= 1) v += __shfl_down(v, off, 64);
        if (lane == 0) out[b] = v + bias;
    }
}

// ---------------------------------------------------------------------------
extern "C" void kernel_launch(void* const* d_in, const int* in_sizes, int n_in,
                              void* d_out, int out_size, void* d_ws, size_t ws_size,
                              hipStream_t stream)
{
    const float* x   = (const float*)d_in[0];   // [8,16,4096]
    const float* Sc  = (const float*)d_in[1];   // [1,4096,4096]
    const float* Sl  = (const float*)d_in[2];   // [1,4096,4096]
    const float* Wc1 = (const float*)d_in[3];
    const float* bc1 = (const float*)d_in[4];
    const float* Wc2 = (const float*)d_in[5];
    const float* bc2 = (const float*)d_in[6];
    const float* Wl1 = (const float*)d_in[7];
    const float* bl1 = (const float*)d_in[8];
    const float* Wl2 = (const float*)d_in[9];
    const float* bl2 = (const float*)d_in[10];
    const float* Wm1 = (const float*)d_in[11];  // [64,65536]
    const float* bm1 = (const float*)d_in[12];
    const float* Wm2 = (const float*)d_in[13];  // [1,64]
    const float* bm2 = (const float*)d_in[14];
    float* out = (float*)d_out;                 // [8,1] f32

    char* ws = (char*)d_ws;                      // proven >= 81.02 MB
    u16*   part = (u16*)(ws);                    // 8 MB partial planes
    u16*   zb1  = (u16*)(ws + (8u  << 20));      // 2 MB
    u16*   yPa  = (u16*)(ws + (12u << 20));      // 2 MB
    u16*   yPb  = (u16*)(ws + (14u << 20));      // 2 MB
    float* h1p  = (float*)(ws + (16u << 20));    // 16 KB (8 slices x 8 x 64)
    u16*   Scb  = (u16*)(ws + (17u << 20));      // 32 MB
    u16*   Slb  = Scb + (size_t)NN * NN;         // 32 MB  (total 81.02 MB)

    const dim3 blk(256);
    const dim3 gridCmb(BB * NN / 256);           // 128
    const dim3 g128(32, 1, 8);                   // M=128: 256 blocks, ITERS=8
    const dim3 g256(32, 2, 4);                   // M=256: 256 blocks, ITERS=16
    const int  pl128 = 128 * NN;                 // plane elems, M=128
    const int  pl256 = 256 * NN;                 // plane elems, M=256

    cvt_x<<<256, blk, 0, stream>>>(x, yPa);

    // Layer 1: clique, Fin=16 (M=128) -> Fout=32.  First pass over Sc reads
    // f32 and writes Scb (bf16) as byproduct.
    diffuse_cvtB<8><<<g128, blk, 0, stream>>>(yPa, Sc, part, Scb);
    reduce_part<8><<<256, blk, 0, stream>>>(part, pl128, zb1);
    diffuse<8><<<g128, blk, 0, stream>>>(zb1, Scb, part);
    combine_relu<16, 32, 8><<<gridCmb, blk, 0, stream>>>(yPa, zb1, part, pl128,
                                                         Wc1, bc1, yPb);
    // Layer 2: clique, Fin=32 (M=256) -> Fout=16
    diffuse<16><<<g256, blk, 0, stream>>>(yPb, Scb, part);
    reduce_part<4><<<512, blk, 0, stream>>>(part, pl256, zb1);
    diffuse<16><<<g256, blk, 0, stream>>>(zb1, Scb, part);
    combine_relu<32, 16, 4><<<gridCmb, blk, 0, stream>>>(yPb, zb1, part, pl256,
                                                         Wc2, bc2, yPa);
    // Layer 3: line, Fin=16 (M=128) -> Fout=32.  First pass over Sl reads
    // f32 and writes Slb (bf16) as byproduct.
    diffuse_cvtB<8><<<g128, blk, 0, stream>>>(yPa, Sl, part, Slb);
    reduce_part<8><<<256, blk, 0, stream>>>(part, pl128, zb1);
    diffuse<8><<<g128, blk, 0, stream>>>(zb1, Slb, part);
    combine_relu<16, 32, 8><<<gridCmb, blk, 0, stream>>>(yPa, zb1, part, pl128,
                                                         Wl1, bl1, yPb);
    // Layer 4: line, Fin=32 (M=256) -> Fout=16
    diffuse<16><<<g256, blk, 0, stream>>>(yPb, Slb, part);
    reduce_part<4><<<512, blk, 0, stream>>>(part, pl256, zb1);
    diffuse<16><<<g256, blk, 0, stream>>>(zb1, Slb, part);
    combine_relu<32, 16, 4><<<gridCmb, blk, 0, stream>>>(yPb, zb1, part, pl256,
                                                         Wl2, bl2, yPa);
    // MLP
    mlp1<<<dim3(64, 8), blk, 0, stream>>>(yPa, Wm1, h1p);
    mlp2<<<1, 64, 0, stream>>>(h1p, bm1, Wm2, bm2, out);
}